// Round 1
// baseline (187.261 us; speedup 1.0000x reference)
//
#include <hip/hip_runtime.h>

// GraphAttentionLayer: B=1, N=4096, F=256, H=8, U=64
//
// e_src cancels in softmax over j =>
//   out[i, u*8+h] = relu( (A @ (w*h))[i, h*64+u] / (A @ w)[i, h] ),  w = exp(e_dst)
// => ONE dense GEMM  C = A(4096x4096) x G(4096x544), G = [w*h (512) | w (8) | 0 (24)]
//
// R6: occupancy attack (R5 counters: MfmaUtil 12%, VALUBusy 10%, Occ 18% ->
// latency-bound at 1 block/CU).
//  k_gemm: BM 64->32, grid (128,4)=512 blocks = 2/CU (16 waves/CU). 8 waves
//  each own n-tile pair {w, w+8} -> zero B duplication, exact 17-tile split
//  (removes the 20/17 clamp waste). Tile 16 round-robined per-wave (ds==w),
//  partials summed by the existing P atomics. launch_bounds(512,4) caps VGPR<=128.
//  k_hg: 64-col (1-head) blocks, grid (128,8)=1024 = 4/CU, LDS 26 KB.
//
// Gtp layout (HW-verified R4): tile (tk=k>>4, nt=n>>5), id=tk*17+nt, 1024 B:
//   u16[ id*512 + ((n&31) + 32*((k&15)>>3))*8 + (k&7) ]
// B-frag(lane) = 16 B at id*1024 + lane*16.
//
// ws: P @0 (4096*544*4 = 8,912,896 B) | Gtp @8912896 (4352 tiles * 1024 B)

typedef unsigned short u16;
typedef unsigned int   u32;
typedef __attribute__((ext_vector_type(8)))  short  short8;    // 8 bf16 (4 VGPR)
typedef __attribute__((ext_vector_type(16))) float  floatx16;  // 32x32 MFMA acc
typedef __attribute__((ext_vector_type(8)))  unsigned short u16x8;
typedef __attribute__((ext_vector_type(4)))  unsigned short u16x4;
typedef __attribute__((ext_vector_type(2)))  unsigned short u16x2;

__device__ __forceinline__ u16 f2bf(float x) {
  u32 u = __float_as_uint(x);
  u += 0x7fffu + ((u >> 16) & 1u);   // RNE
  return (u16)(u >> 16);
}

__device__ __forceinline__ void async_ld16(const void* g, void* l) {
  __builtin_amdgcn_global_load_lds((const __attribute__((address_space(1))) void*)g,
                                   (__attribute__((address_space(3))) void*)l,
                                   16, 0, 0);
}

// ---------------------------------------------------------------------------
// Kernel 1: h = X@W (fp32, exact), e_dst -> w = exp, write Gtp (B-frag layout).
// Block: 32 j-rows x 64 c-cols (1 whole head => e-sums block-local).
// Thread: 2j x 4c. K in 4 single-buffered chunks of 64 (W async->LDS, X
// transposed). Grid (128, 8) = 1024 blocks = 4/CU (16 waves/CU). Also zeroes P.
// ---------------------------------------------------------------------------
__global__ __launch_bounds__(256, 4) void k_hg(const float* __restrict__ X,
                                               const float* __restrict__ W,
                                               const float* __restrict__ av,
                                               u16* __restrict__ Gtp,
                                               float* __restrict__ P) {
  __shared__ __align__(16) float Wc[64 * 64];    // 16 KB
  __shared__ __align__(16) float xs[64 * 36];    // 9 KB (pad 36 breaks stride)
  __shared__ float eL[32];
  __shared__ float w8L[32];
  const int t  = threadIdx.x;
  const int j0 = blockIdx.x * 32;
  const int y  = blockIdx.y;           // head y
  const int c0 = y * 64;
  const int cq = t & 15, tj = t >> 4;  // 16 c-threads x 16 j-threads

  // zero this block's P slab (557,056 float4 / 1024 blocks = 544 each)
  {
    float4* P4 = (float4*)P;
    const int base = ((int)blockIdx.y * 128 + (int)blockIdx.x) * 544;
    float4 z = {0.f, 0.f, 0.f, 0.f};
    P4[base + t]       = z;
    P4[base + 256 + t] = z;
    if (t < 32) P4[base + 512 + t] = z;
  }
  if (t < 32) eL[t] = 0.f;

  float acc[2][4];
#pragma unroll
  for (int a = 0; a < 2; ++a)
#pragma unroll
    for (int b = 0; b < 4; ++b) acc[a][b] = 0.f;

  const int xjj = t >> 3, xoff = (t & 7) * 8;

  for (int cc = 0; cc < 4; ++cc) {
    // stage W chunk (64 k x 64 c) via async global->LDS
#pragma unroll
    for (int l = 0; l < 4; ++l) {
      int id = l * 256 + t;
      int kk = id >> 4, ch = id & 15;
      async_ld16(W + (size_t)(cc * 64 + kk) * 512 + c0 + ch * 4,
                 (char*)&Wc[0] + (size_t)(l * 256 + (t & 192)) * 16);
    }
    // stage X chunk transposed: xs[k][j]
    {
      const float* xp = X + (size_t)(j0 + xjj) * 256 + cc * 64 + xoff;
      float4 v0 = *(const float4*)xp;
      float4 v1 = *(const float4*)(xp + 4);
      xs[(xoff + 0) * 36 + xjj] = v0.x; xs[(xoff + 1) * 36 + xjj] = v0.y;
      xs[(xoff + 2) * 36 + xjj] = v0.z; xs[(xoff + 3) * 36 + xjj] = v0.w;
      xs[(xoff + 4) * 36 + xjj] = v1.x; xs[(xoff + 5) * 36 + xjj] = v1.y;
      xs[(xoff + 6) * 36 + xjj] = v1.z; xs[(xoff + 7) * 36 + xjj] = v1.w;
    }
    __syncthreads();
#pragma unroll 4
    for (int kk = 0; kk < 64; ++kk) {
      float4 w4 = *(const float4*)(&Wc[kk * 64 + cq * 4]);
      float2 xa = *(const float2*)(&xs[kk * 36 + tj * 2]);   // broadcast
      acc[0][0] += xa.x * w4.x; acc[0][1] += xa.x * w4.y; acc[0][2] += xa.x * w4.z; acc[0][3] += xa.x * w4.w;
      acc[1][0] += xa.y * w4.x; acc[1][1] += xa.y * w4.y; acc[1][2] += xa.y * w4.z; acc[1][3] += xa.y * w4.w;
    }
    __syncthreads();
  }

  // e_dst partials (1 block-local head)
  {
    const float4 ad = *(const float4*)(av + 64 + cq * 4);
#pragma unroll
    for (int jv = 0; jv < 2; ++jv) {
      float ep = acc[jv][0] * ad.x + acc[jv][1] * ad.y + acc[jv][2] * ad.z + acc[jv][3] * ad.w;
      atomicAdd(&eL[tj * 2 + jv], ep);
    }
  }
  __syncthreads();
  if (t < 32) {
    float e = fminf(30.f, fmaxf(-30.f, eL[t]));
    w8L[t] = __expf(e);
  }
  __syncthreads();

  // scaled bf16 stores in B-frag layout (j = j0 + tj*2 + jv)
  const int tk  = (j0 >> 4) + (tj >> 3);
  const int khh = (tj >> 2) & 1;             // ((tj*2)&15)>>3
  const int jlo = (tj & 3) * 2;              // (tj*2)&7
  const float wA = w8L[tj * 2], wB = w8L[tj * 2 + 1];
#pragma unroll
  for (int cv = 0; cv < 4; ++cv) {
    int n  = c0 + cq * 4 + cv;
    int nt = n >> 5;
    u16x2 o;
    o[0] = f2bf(acc[0][cv] * wA);
    o[1] = f2bf(acc[1][cv] * wB);
    *(u16x2*)(Gtp + (size_t)(tk * 17 + nt) * 512 + ((n & 31) + 32 * khh) * 8 + jlo) = o;
  }
  // den row (n = 512 + y): this block's head x 32 rows
  if (t < 32) {
    int jj = t, j = j0 + jj;
    Gtp[(size_t)((j >> 4) * 17 + 16) * 512 + (y + 32 * ((jj & 15) >> 3)) * 8 + (jj & 7)] =
        f2bf(w8L[jj]);
  }
  // zero pad (n in [520,544)): slots [8,32) and [40,64) of tile nt=16; y==7 does it
  if (y == 7 && t < 96) {
    int tk2 = t / 48, r = t - tk2 * 48;
    int slot = (r < 24) ? (8 + r) : (16 + r);
    u16x8 z = {0, 0, 0, 0, 0, 0, 0, 0};
    *(u16x8*)(Gtp + (size_t)(((j0 >> 4) + tk2) * 17 + 16) * 512 + slot * 8) = z;
  }
}

// ---------------------------------------------------------------------------
// Kernel 2: C += A(fp32,{0,1}) x G^T via 32x32x16 bf16 MFMA, atomicAdd into P.
// Block: 512 threads = 8 waves, BM=32: every wave owns n-tile pair {w, w+8}
// (exact 17-tile split; tile 16 round-robined at ds==w, partials summed by the
// P atomics). A: K=256 chunks, fp32->bf16, XOR-swizzled double-buffered LDS
// (2x16 KB); 7 barriers/block. B: direct dwordx4 from L2-hot Gtp, no barrier
// in the 8-dstep inner loop. Grid (128, Z=4) = 512 blocks = 2/CU.
// ---------------------------------------------------------------------------
__global__ __launch_bounds__(512, 4) void k_gemm(const float* __restrict__ A,
                                                 const u16* __restrict__ Gtp,
                                                 float* __restrict__ P) {
  __shared__ __align__(16) u16 As[2][32 * 256];  // 2 x 16 KB
  const int t    = threadIdx.x;
  const int i0   = blockIdx.x * 32;
  const int kt0  = blockIdx.y * 1024;
  const int w    = t >> 6, lane = t & 63;
  const int ml   = lane & 31, kh = lane >> 5;

  floatx16 acc[3];
#pragma unroll
  for (int q = 0; q < 3; ++q)
#pragma unroll
    for (int r = 0; r < 16; ++r) acc[q][r] = 0.f;

  // A staging: thread -> row ar (0..31), q-th float4 at k = (t&15)*4 + q*64
  const int ar  = t >> 4;
  const int af  = (t & 15) * 4;
  const float* pa = A + (size_t)(i0 + ar) * 4096 + kt0 + af;
  const int sbase = ar * 256 + (t & 1) * 4;   // + swizzled chunk*8
  const int scb   = (t & 15) >> 1;            // chunk = q*8 + scb
  const int arx   = ar & 7;

  // A-frag reads: row m = ml, chunk c -> physical c^(ml&7)
  const int arow = ml * 256;
  const int mx   = ml & 7;
  const int nt0  = w, nt1 = w + 8;

  float4 areg[4];
#pragma unroll
  for (int q = 0; q < 4; ++q) areg[q] = *(const float4*)(pa + q * 64);
#pragma unroll
  for (int q = 0; q < 4; ++q) {
    u16x4 v = {f2bf(areg[q].x), f2bf(areg[q].y), f2bf(areg[q].z), f2bf(areg[q].w)};
    *(u16x4*)(&As[0][sbase + ((q * 8 + scb) ^ arx) * 8]) = v;
  }
  __syncthreads();

  for (int cc = 0; cc < 4; ++cc) {
    const int cb = cc & 1;
    if (cc < 3) {                    // prefetch next chunk early (hidden by compute)
#pragma unroll
      for (int q = 0; q < 4; ++q)
        areg[q] = *(const float4*)(pa + (cc + 1) * 256 + q * 64);
    }
    const int ktb = (kt0 >> 4) + cc * 16;
#pragma unroll 2
    for (int ds = 0; ds < 8; ++ds) {
      short8 b00 = *(const short8*)(Gtp + (size_t)((ktb + ds * 2) * 17 + nt0) * 512 + lane * 8);
      short8 b01 = *(const short8*)(Gtp + (size_t)((ktb + ds * 2) * 17 + nt1) * 512 + lane * 8);
      short8 b10 = *(const short8*)(Gtp + (size_t)((ktb + ds * 2 + 1) * 17 + nt0) * 512 + lane * 8);
      short8 b11 = *(const short8*)(Gtp + (size_t)((ktb + ds * 2 + 1) * 17 + nt1) * 512 + lane * 8);
      short8 a0 = *(const short8*)(&As[cb][arow + ((ds * 4 + kh) ^ mx) * 8]);
      short8 a1 = *(const short8*)(&As[cb][arow + ((ds * 4 + 2 + kh) ^ mx) * 8]);
      acc[0] = __builtin_amdgcn_mfma_f32_32x32x16_bf16(a0, b00, acc[0], 0, 0, 0);
      acc[1] = __builtin_amdgcn_mfma_f32_32x32x16_bf16(a0, b01, acc[1], 0, 0, 0);
      acc[0] = __builtin_amdgcn_mfma_f32_32x32x16_bf16(a1, b10, acc[0], 0, 0, 0);
      acc[1] = __builtin_amdgcn_mfma_f32_32x32x16_bf16(a1, b11, acc[1], 0, 0, 0);
    }
    // tile 16 (den cols): this wave's k-slice (ds == w), keeps hot loop branch-free
    {
      short8 a0 = *(const short8*)(&As[cb][arow + ((w * 4 + kh) ^ mx) * 8]);
      short8 a1 = *(const short8*)(&As[cb][arow + ((w * 4 + 2 + kh) ^ mx) * 8]);
      short8 c0v = *(const short8*)(Gtp + (size_t)((ktb + w * 2) * 17 + 16) * 512 + lane * 8);
      short8 c1v = *(const short8*)(Gtp + (size_t)((ktb + w * 2 + 1) * 17 + 16) * 512 + lane * 8);
      acc[2] = __builtin_amdgcn_mfma_f32_32x32x16_bf16(a0, c0v, acc[2], 0, 0, 0);
      acc[2] = __builtin_amdgcn_mfma_f32_32x32x16_bf16(a1, c1v, acc[2], 0, 0, 0);
    }
    if (cc < 3) {
      __syncthreads();               // readers of other buffer done
#pragma unroll
      for (int q = 0; q < 4; ++q) {
        u16x4 v = {f2bf(areg[q].x), f2bf(areg[q].y), f2bf(areg[q].z), f2bf(areg[q].w)};
        *(u16x4*)(&As[cb ^ 1][sbase + ((q * 8 + scb) ^ arx) * 8]) = v;
      }
      __syncthreads();               // writes visible
    }
  }

  // epilogue: C/D layout col=lane&31, row=(r&3)+8*(r>>2)+4*(lane>>5); atomics
  const int rbase = i0 + 4 * kh;
#pragma unroll
  for (int q = 0; q < 2; ++q) {
    const int n = (w + 8 * q) * 32 + ml;   // < 512 always
#pragma unroll
    for (int r = 0; r < 16; ++r) {
      int row = rbase + (r & 3) + 8 * (r >> 2);
      atomicAdd(P + (size_t)row * 544 + n, acc[q][r]);
    }
  }
  if (ml < 8) {                            // den cols 512..519; partial k-sums from all waves
    const int n = 512 + ml;
#pragma unroll
    for (int r = 0; r < 16; ++r) {
      int row = rbase + (r & 3) + 8 * (r >> 2);
      atomicAdd(P + (size_t)row * 544 + n, acc[2][r]);
    }
  }
}

// ---------------------------------------------------------------------------
// Kernel 3: out[i, u*8+h] = relu( P[i][h*64+u] / P[i][512+h] ). 2 rows/block.
// ---------------------------------------------------------------------------
__global__ __launch_bounds__(256) void k_out(const float* __restrict__ P,
                                             float* __restrict__ out) {
  __shared__ float ps[2][544];
  const int t    = threadIdx.x;
  const int half = t >> 7, lt = t & 127;
  const int i    = blockIdx.x * 2 + half;
  const float* pr = P + (size_t)i * 544;
  for (int q = lt; q < 544; q += 128) ps[half][q] = pr[q];
  __syncthreads();
  for (int c = lt; c < 512; c += 128) {           // c = u*8 + h
    int u = c >> 3, hd = c & 7;
    float o = ps[half][hd * 64 + u] / ps[half][512 + hd];
    out[(size_t)i * 512 + c] = fmaxf(o, 0.f);
  }
}

extern "C" void kernel_launch(void* const* d_in, const int* in_sizes, int n_in,
                              void* d_out, int out_size, void* d_ws, size_t ws_size,
                              hipStream_t stream) {
  const float* X  = (const float*)d_in[0];
  const float* A  = (const float*)d_in[1];
  const float* W  = (const float*)d_in[2];
  const float* av = (const float*)d_in[3];
  float* out = (float*)d_out;
  char*  ws  = (char*)d_ws;

  float* P   = (float*)ws;                 // 4096*544*4
  u16*   Gtp = (u16*)(ws + 8912896);       // 256*17 tiles * 1024 B

  k_hg<<<dim3(128, 8), 256, 0, stream>>>(X, W, av, Gtp, P);
  k_gemm<<<dim3(128, 4), 512, 0, stream>>>(A, Gtp, P);
  k_out<<<2048, 256, 0, stream>>>(P, out);
}

// Round 2
// 159.981 us; speedup vs baseline: 1.1705x; 1.1705x over previous
//
#include <hip/hip_runtime.h>

// GraphAttentionLayer: B=1, N=4096, F=256, H=8, U=64
//
// e_src cancels in softmax over j =>
//   out[i, u*8+h] = relu( (A @ (w*h))[i, h*64+u] / (A @ w)[i, h] ),  w = exp(e_dst)
// => ONE dense GEMM  C = A(4096x4096) x G(4096x544), G = [w*h (512) | w (8) | 0 (24)]
//
// R7: atomic elimination + ILP restore (R6 post-mortem: occupancy 18->37% made
// k_gemm SLOWER; 8.9M fp32 atomicAdds were the invariant ~45us floor, and
// launch_bounds(512,4) squeezed arch VGPRs to 60 killing load ILP).
//  k_gemm: Z=2 k-split -> 2 disjoint P slabs, PLAIN stores (den cols reduced
//  across waves in LDS first). launch_bounds(512,2) (1 blk/CU, VGPR<=256),
//  4 independent MFMA acc chains + den chain. XCD-aware block decode: each
//  z-slice's 2.2 MB Gtp k-slab pinned to 4 XCDs -> B-loads L2-resident.
//  k_hg: reverted to R5-proven 128-col 2-head version (R6 halving raised LDS
//  traffic 1.5x), P memset dropped (plain stores need no zeroed P).
//  k_out: sums the 2 slabs.
//
// Gtp layout (HW-verified R4): tile (tk=k>>4, nt=n>>5), id=tk*17+nt, 1024 B:
//   u16[ id*512 + ((n&31) + 32*((k&15)>>3))*8 + (k&7) ]
// B-frag(lane) = 16 B at id*1024 + lane*16.
//
// ws: P (2 slabs of 4096 x 520 fp32 = 17,039,360 B) | Gtp @17039360 (4352*1024 B)

typedef unsigned short u16;
typedef unsigned int   u32;
typedef __attribute__((ext_vector_type(8)))  short  short8;    // 8 bf16 (4 VGPR)
typedef __attribute__((ext_vector_type(16))) float  floatx16;  // 32x32 MFMA acc
typedef __attribute__((ext_vector_type(8)))  unsigned short u16x8;
typedef __attribute__((ext_vector_type(4)))  unsigned short u16x4;

__device__ __forceinline__ u16 f2bf(float x) {
  u32 u = __float_as_uint(x);
  u += 0x7fffu + ((u >> 16) & 1u);   // RNE
  return (u16)(u >> 16);
}

__device__ __forceinline__ void async_ld16(const void* g, void* l) {
  __builtin_amdgcn_global_load_lds((const __attribute__((address_space(1))) void*)g,
                                   (__attribute__((address_space(3))) void*)l,
                                   16, 0, 0);
}

// ---------------------------------------------------------------------------
// Kernel 1: h = X@W (fp32, exact), e_dst -> w = exp, write Gtp (B-frag layout).
// Block: 32 j-rows x 128 c-cols (2 whole heads => e-sums block-local).
// Thread: 4j x 4c. K in 4 single-buffered chunks of 64 (W async->LDS, X
// transposed). Grid (128, 4) = 512 blocks = 2/CU.  (R5-proven version.)
// ---------------------------------------------------------------------------
__global__ __launch_bounds__(256) void k_hg(const float* __restrict__ X,
                                            const float* __restrict__ W,
                                            const float* __restrict__ av,
                                            u16* __restrict__ Gtp) {
  __shared__ __align__(16) float Wc[64 * 128];   // 32 KB
  __shared__ __align__(16) float xs[64 * 36];    // 9 KB (pad 36 breaks stride)
  __shared__ float eL[64];
  __shared__ float w8L[64];
  const int t  = threadIdx.x;
  const int j0 = blockIdx.x * 32;
  const int y  = blockIdx.y;           // heads 2y, 2y+1
  const int c0 = y * 128;
  const int cq = t & 31, tj = t >> 5;

  if (t < 64) eL[t] = 0.f;

  float acc[4][4];
#pragma unroll
  for (int a = 0; a < 4; ++a)
#pragma unroll
    for (int b = 0; b < 4; ++b) acc[a][b] = 0.f;

  const int xjj = t >> 3, xoff = (t & 7) * 8;

  for (int cc = 0; cc < 4; ++cc) {
    // stage W chunk (64 k x 128 c) via async global->LDS
#pragma unroll
    for (int l = 0; l < 8; ++l) {
      int id = l * 256 + t;
      int kk = id >> 5, ch = id & 31;
      async_ld16(W + (size_t)(cc * 64 + kk) * 512 + c0 + ch * 4,
                 (char*)&Wc[0] + (size_t)(l * 256 + (t & 192)) * 16);
    }
    // stage X chunk transposed: xs[k][j]
    {
      const float* xp = X + (size_t)(j0 + xjj) * 256 + cc * 64 + xoff;
      float4 v0 = *(const float4*)xp;
      float4 v1 = *(const float4*)(xp + 4);
      xs[(xoff + 0) * 36 + xjj] = v0.x; xs[(xoff + 1) * 36 + xjj] = v0.y;
      xs[(xoff + 2) * 36 + xjj] = v0.z; xs[(xoff + 3) * 36 + xjj] = v0.w;
      xs[(xoff + 4) * 36 + xjj] = v1.x; xs[(xoff + 5) * 36 + xjj] = v1.y;
      xs[(xoff + 6) * 36 + xjj] = v1.z; xs[(xoff + 7) * 36 + xjj] = v1.w;
    }
    __syncthreads();
#pragma unroll 4
    for (int kk = 0; kk < 64; ++kk) {
      float4 w4 = *(const float4*)(&Wc[kk * 128 + cq * 4]);
      float4 xa = *(const float4*)(&xs[kk * 36 + tj * 4]);   // broadcast
      acc[0][0] += xa.x * w4.x; acc[0][1] += xa.x * w4.y; acc[0][2] += xa.x * w4.z; acc[0][3] += xa.x * w4.w;
      acc[1][0] += xa.y * w4.x; acc[1][1] += xa.y * w4.y; acc[1][2] += xa.y * w4.z; acc[1][3] += xa.y * w4.w;
      acc[2][0] += xa.z * w4.x; acc[2][1] += xa.z * w4.y; acc[2][2] += xa.z * w4.z; acc[2][3] += xa.z * w4.w;
      acc[3][0] += xa.w * w4.x; acc[3][1] += xa.w * w4.y; acc[3][2] += xa.w * w4.z; acc[3][3] += xa.w * w4.w;
    }
    __syncthreads();
  }

  // e_dst partials (2 block-local heads)
  const int lh = cq >> 4;
  {
    const float4 ad = *(const float4*)(av + 64 + (cq & 15) * 4);
#pragma unroll
    for (int jv = 0; jv < 4; ++jv) {
      float ep = acc[jv][0] * ad.x + acc[jv][1] * ad.y + acc[jv][2] * ad.z + acc[jv][3] * ad.w;
      atomicAdd(&eL[(tj * 4 + jv) * 2 + lh], ep);
    }
  }
  __syncthreads();
  if (t < 64) {
    float e = fminf(30.f, fmaxf(-30.f, eL[t]));
    w8L[t] = __expf(e);
  }
  __syncthreads();

  // scaled bf16 stores in B-frag layout
  const int tk  = (j0 >> 4) + (tj >> 2);     // j>>4 for j = j0 + tj*4 + jv
  const int khh = (tj >> 1) & 1;             // (j&15)>>3
  const int jlo = (tj & 1) * 4;              // j&7 base
#pragma unroll
  for (int cv = 0; cv < 4; ++cv) {
    int n  = c0 + cq * 4 + cv;
    int nt = n >> 5;
    u16x4 o;
#pragma unroll
    for (int jv = 0; jv < 4; ++jv)
      o[jv] = f2bf(acc[jv][cv] * w8L[(tj * 4 + jv) * 2 + lh]);
    *(u16x4*)(Gtp + (size_t)(tk * 17 + nt) * 512 + ((n & 31) + 32 * khh) * 8 + jlo) = o;
  }
  // den rows (n = 512 + h, this block's 2 heads x 32 rows)
  if (t < 64) {
    int jj = t >> 1, lh2 = t & 1, h = 2 * y + lh2, j = j0 + jj;
    Gtp[(size_t)((j >> 4) * 17 + 16) * 512 + (h + 32 * ((jj & 15) >> 3)) * 8 + (jj & 7)] =
        f2bf(w8L[jj * 2 + lh2]);
  }
  // zero pad (n in [520,544)): slots [8,32) and [40,64) of tile nt=16; y==3 does it
  if (y == 3 && t < 96) {
    int tk2 = t / 48, r = t - tk2 * 48;
    int slot = (r < 24) ? (8 + r) : (16 + r);
    u16x8 z = {0, 0, 0, 0, 0, 0, 0, 0};
    *(u16x8*)(Gtp + (size_t)(((j0 >> 4) + tk2) * 17 + 16) * 512 + slot * 8) = z;
  }
}

// ---------------------------------------------------------------------------
// Kernel 2: Pz = A(fp32,{0,1}) x G^T via 32x32x16 bf16 MFMA, PLAIN stores.
// Block: 512 threads = 8 waves, BM=32: wave w owns n-tile pair {w, w+8}
// (exact 17-tile split; tile 16 round-robined at ds==w, summed across waves
// via LDS reduce, across z via k_out). Z=2 -> K=2048 per block, 8 chunks of
// 256, XOR-swizzled double-buffered LDS A. 4 independent MFMA chains.
// Grid 256 blocks, XCD-decoded: z = xcd>>2 -> each z's 2.2 MB Gtp k-slab is
// L2-resident on its 4 XCDs.
// ---------------------------------------------------------------------------
__global__ __launch_bounds__(512, 2) void k_gemm(const float* __restrict__ A,
                                                 const u16* __restrict__ Gtp,
                                                 float* __restrict__ P) {
  __shared__ __align__(16) u16 As[2][32 * 256];  // 2 x 16 KB
  const int t    = threadIdx.x;
  const int bid  = blockIdx.x;
  const int xcd  = bid & 7, seq = bid >> 3;      // HW round-robins blockIdx%8 -> XCD
  const int z    = xcd >> 2;                     // k-slice 0..1
  const int i0   = (((xcd & 3) << 5) + seq) * 32;  // strip 0..127
  const int kt0  = z * 2048;
  const int w    = t >> 6, lane = t & 63;
  const int ml   = lane & 31, kh = lane >> 5;

  floatx16 c0a, c0b, c1a, c1b, cd;
#pragma unroll
  for (int r = 0; r < 16; ++r) { c0a[r] = 0.f; c0b[r] = 0.f; c1a[r] = 0.f; c1b[r] = 0.f; cd[r] = 0.f; }

  // A staging: thread -> row ar (0..31), q-th float4 at k = (t&15)*4 + q*64
  const int ar  = t >> 4;
  const int af  = (t & 15) * 4;
  const float* pa = A + (size_t)(i0 + ar) * 4096 + kt0 + af;
  const int sbase = ar * 256 + (t & 1) * 4;   // + swizzled chunk*8
  const int scb   = (t & 15) >> 1;            // chunk = q*8 + scb
  const int arx   = ar & 7;

  // A-frag reads: row m = ml, chunk c -> physical c^(ml&7)
  const int arow = ml * 256;
  const int mx   = ml & 7;
  const int nt0  = w, nt1 = w + 8;

  float4 areg[4];
#pragma unroll
  for (int q = 0; q < 4; ++q) areg[q] = *(const float4*)(pa + q * 64);
#pragma unroll
  for (int q = 0; q < 4; ++q) {
    u16x4 v = {f2bf(areg[q].x), f2bf(areg[q].y), f2bf(areg[q].z), f2bf(areg[q].w)};
    *(u16x4*)(&As[0][sbase + ((q * 8 + scb) ^ arx) * 8]) = v;
  }
  __syncthreads();

  for (int cc = 0; cc < 8; ++cc) {
    const int cb = cc & 1;
    if (cc < 7) {                    // prefetch next chunk early (hidden by compute)
#pragma unroll
      for (int q = 0; q < 4; ++q)
        areg[q] = *(const float4*)(pa + (cc + 1) * 256 + q * 64);
    }
    const int ktb = (kt0 >> 4) + cc * 16;
#pragma unroll 2
    for (int ds = 0; ds < 8; ++ds) {
      short8 b00 = *(const short8*)(Gtp + (size_t)((ktb + ds * 2) * 17 + nt0) * 512 + lane * 8);
      short8 b01 = *(const short8*)(Gtp + (size_t)((ktb + ds * 2) * 17 + nt1) * 512 + lane * 8);
      short8 b10 = *(const short8*)(Gtp + (size_t)((ktb + ds * 2 + 1) * 17 + nt0) * 512 + lane * 8);
      short8 b11 = *(const short8*)(Gtp + (size_t)((ktb + ds * 2 + 1) * 17 + nt1) * 512 + lane * 8);
      short8 a0 = *(const short8*)(&As[cb][arow + ((ds * 4 + kh) ^ mx) * 8]);
      short8 a1 = *(const short8*)(&As[cb][arow + ((ds * 4 + 2 + kh) ^ mx) * 8]);
      c0a = __builtin_amdgcn_mfma_f32_32x32x16_bf16(a0, b00, c0a, 0, 0, 0);
      c1a = __builtin_amdgcn_mfma_f32_32x32x16_bf16(a0, b01, c1a, 0, 0, 0);
      c0b = __builtin_amdgcn_mfma_f32_32x32x16_bf16(a1, b10, c0b, 0, 0, 0);
      c1b = __builtin_amdgcn_mfma_f32_32x32x16_bf16(a1, b11, c1b, 0, 0, 0);
    }
    // tile 16 (den cols): this wave's k-slice (ds == w), keeps hot loop branch-free
    {
      short8 a0 = *(const short8*)(&As[cb][arow + ((w * 4 + kh) ^ mx) * 8]);
      short8 a1 = *(const short8*)(&As[cb][arow + ((w * 4 + 2 + kh) ^ mx) * 8]);
      short8 d0 = *(const short8*)(Gtp + (size_t)((ktb + w * 2) * 17 + 16) * 512 + lane * 8);
      short8 d1 = *(const short8*)(Gtp + (size_t)((ktb + w * 2 + 1) * 17 + 16) * 512 + lane * 8);
      cd = __builtin_amdgcn_mfma_f32_32x32x16_bf16(a0, d0, cd, 0, 0, 0);
      cd = __builtin_amdgcn_mfma_f32_32x32x16_bf16(a1, d1, cd, 0, 0, 0);
    }
    if (cc < 7) {
      __syncthreads();               // readers of other buffer done
#pragma unroll
      for (int q = 0; q < 4; ++q) {
        u16x4 v = {f2bf(areg[q].x), f2bf(areg[q].y), f2bf(areg[q].z), f2bf(areg[q].w)};
        *(u16x4*)(&As[cb ^ 1][sbase + ((q * 8 + scb) ^ arx) * 8]) = v;
      }
      __syncthreads();               // writes visible
    }
  }

  // ---- epilogue: plain stores to slab z (no atomics) ----
  float* Pz = P + (size_t)z * (4096 * 520);
  const int rbase = i0 + 4 * kh;

  floatx16 accA, accB;
#pragma unroll
  for (int r = 0; r < 16; ++r) { accA[r] = c0a[r] + c0b[r]; accB[r] = c1a[r] + c1b[r]; }

  // C/D layout: col = lane&31, row = (r&3) + 8*(r>>2) + 4*(lane>>5)
#pragma unroll
  for (int r = 0; r < 16; ++r) {
    int row = rbase + (r & 3) + 8 * (r >> 2);
    Pz[(size_t)row * 520 + nt0 * 32 + ml] = accA[r];
    Pz[(size_t)row * 520 + nt1 * 32 + ml] = accB[r];
  }

  // den cols 512..519: reduce cd across the 8 waves via LDS (reuse As[0])
  float* dred = (float*)&As[0][0];   // 8 waves x 32 rows x 8 cols = 8 KB
  if (ml < 8) {
#pragma unroll
    for (int r = 0; r < 16; ++r) {
      int row = 4 * kh + (r & 3) + 8 * (r >> 2);
      dred[(w * 32 + row) * 8 + ml] = cd[r];
    }
  }
  __syncthreads();
  if (t < 256) {
    int row = t >> 3, c = t & 7;
    float s = 0.f;
#pragma unroll
    for (int ww = 0; ww < 8; ++ww) s += dred[(ww * 32 + row) * 8 + c];
    Pz[(size_t)(i0 + row) * 520 + 512 + c] = s;
  }
}

// ---------------------------------------------------------------------------
// Kernel 3: out[i, u*8+h] = relu( SUMz Pz[i][h*64+u] / SUMz Pz[i][512+h] ).
// 2 rows/block, 2048 blocks.
// ---------------------------------------------------------------------------
__global__ __launch_bounds__(256) void k_out(const float* __restrict__ P,
                                             float* __restrict__ out) {
  __shared__ float ps[2][520];
  const size_t SL = (size_t)4096 * 520;
  const int t    = threadIdx.x;
  const int half = t >> 7, lt = t & 127;
  const int i    = blockIdx.x * 2 + half;
  const float* pr = P + (size_t)i * 520;
  for (int q = lt; q < 520; q += 128) ps[half][q] = pr[q] + pr[SL + q];
  __syncthreads();
  for (int c = lt; c < 512; c += 128) {           // c = u*8 + h
    int u = c >> 3, hd = c & 7;
    float o = ps[half][hd * 64 + u] / ps[half][512 + hd];
    out[(size_t)i * 512 + c] = fmaxf(o, 0.f);
  }
}

extern "C" void kernel_launch(void* const* d_in, const int* in_sizes, int n_in,
                              void* d_out, int out_size, void* d_ws, size_t ws_size,
                              hipStream_t stream) {
  const float* X  = (const float*)d_in[0];
  const float* A  = (const float*)d_in[1];
  const float* W  = (const float*)d_in[2];
  const float* av = (const float*)d_in[3];
  float* out = (float*)d_out;
  char*  ws  = (char*)d_ws;

  float* P   = (float*)ws;                 // 2 slabs x 4096 x 520 fp32
  u16*   Gtp = (u16*)(ws + 17039360);      // 256*17 tiles * 1024 B

  k_hg<<<dim3(128, 4), 256, 0, stream>>>(X, W, av, Gtp);
  k_gemm<<<256, 512, 0, stream>>>(A, Gtp, P);
  k_out<<<2048, 256, 0, stream>>>(P, out);
}